// Round 5
// baseline (214.610 us; speedup 1.0000x reference)
//
#include <hip/hip_runtime.h>
#include <math.h>

#define B_ 64
#define F_ 32
#define S_ 512
#define P_ 96
#define E_ 8
#define H_ 2048
#define M_ 2048   // B_*F_ rows, m = b*F_ + f

// ---- k_experts: 512 threads (8 waves), full-LDS 160KiB, 32 big K-steps ----
// r4 post-mortem: per-sync-step cost is ~constant (2-3Kcy: same-step GLL16
// drain + barrier), so perf ~ 1/steps * work-per-step. r4 halved work/step ->
// slower despite 2x occupancy. This round: BK=128, 128x128 tiles:
//   W1 dbuf 64KB + X dbuf 64KB + Hs 32KB = 163840B (exactly 160KiB LDS)
//   NHT=8 x NKC=4 = 32 K-steps of 32 MFMA/wave (r1: 64x16, r4: 64x8)
// Uniform 16B-granule XOR-(row&15) swizzle on all tiles (256B rows would be
// 16-way bank-conflicted): pre-swizzled GLL16 global source + XOR on ds_read.
#define BM 128            // m rows per block
#define BH 128            // h per chunk
#define BK 128            // k per staged tile
#define ZSPLIT 2
#define HPZ (H_ / ZSPLIT) // 1024 h per z-block
#define NHT (HPZ / BH)    // 8 h-chunks per block
#define NKC (S_ / BK)     // 4 k-steps per chunk

typedef __bf16 bf16x8 __attribute__((ext_vector_type(8)));
typedef __bf16 bf16x4 __attribute__((ext_vector_type(4)));
typedef float f32x4 __attribute__((ext_vector_type(4)));

#define MFMA16(a, b, c) __builtin_amdgcn_mfma_f32_16x16x32_bf16((a), (b), (c), 0, 0, 0)

// async global->LDS, 16B per lane; LDS dest is wave-uniform base + lane*16
#define GLL16(gp, lp) __builtin_amdgcn_global_load_lds(                     \
    (const __attribute__((address_space(1))) void*)(gp),                    \
    (__attribute__((address_space(3))) void*)(lp), 16, 0, 0)

// sigmoid-approx gelu: x * sigmoid(1.702 x)  (absmax 0.0098 measured — 17x margin)
__device__ __forceinline__ float fast_gelu(float x) {
  float e = __builtin_amdgcn_exp2f(-2.45546696f * x);
  return x * __builtin_amdgcn_rcpf(1.0f + e);
}

// =================== k_prep_w1 (2048 blocks): W1 [E][S][H] f32 -> w1t [E][H][S] bf16 ===================
__global__ __launch_bounds__(256) void k_prep_w1(const float* __restrict__ W1,
                                                 __bf16* __restrict__ w1t) {
  __shared__ float tile[64 * 65];
  const int blk = blockIdx.x;
  const int tid = threadIdx.x;
  int e = blk >> 8, tt = blk & 255;
  int si = tt >> 5, hi = tt & 31;
  const float* src = W1 + (size_t)e * S_ * H_ + (size_t)(si * 64) * H_ + hi * 64;
  {
    int row = tid >> 2;
    int cb = (tid & 3) * 16;
#pragma unroll
    for (int k = 0; k < 4; ++k) {
      f32x4 v = *(const f32x4*)(src + (size_t)row * H_ + cb + k * 4);
#pragma unroll
      for (int u = 0; u < 4; ++u) tile[row * 65 + cb + k * 4 + u] = v[u];
    }
  }
  __syncthreads();
  {
    int h = tid >> 2;
    int sb = (tid & 3) * 16;
    __bf16* dst = w1t + (size_t)e * H_ * S_ + (size_t)(hi * 64 + h) * S_ + si * 64 + sb;
    bf16x8 o0, o1;
#pragma unroll
    for (int k = 0; k < 8; ++k) o0[k] = (__bf16)tile[(sb + k) * 65 + h];
#pragma unroll
    for (int k = 0; k < 8; ++k) o1[k] = (__bf16)tile[(sb + 8 + k) * 65 + h];
    *(bf16x8*)dst = o0;
    *(bf16x8*)(dst + 8) = o1;
  }
}

// =================== k_prep_rest (1728 blocks): W2 transpose + x convert + gates + out-zero ===================
__global__ __launch_bounds__(256) void k_prep_rest(const float* __restrict__ x,
                                                   const float* __restrict__ te,
                                                   const float* __restrict__ Wg,
                                                   const float* __restrict__ bg,
                                                   const float* __restrict__ W2,
                                                   __bf16* __restrict__ xbf,
                                                   __bf16* __restrict__ w2t,
                                                   float* __restrict__ gates,
                                                   float* __restrict__ out) {
  __shared__ float tile[64 * 65];
  const int blk = blockIdx.x;
  const int tid = threadIdx.x;

  if (blk < 512) {                        // ---- W2 transpose: tile 64h x 48p
    int t = blk;
    int e = t >> 6, hi = (t >> 1) & 31, ph = t & 1;
    const float* src = W2 + (size_t)e * H_ * P_ + (size_t)(hi * 64) * P_ + ph * 48;
    {
      int h = tid & 63;
      int seg = tid >> 6;
#pragma unroll
      for (int k = 0; k < 3; ++k) {
        f32x4 v = *(const f32x4*)(src + (size_t)h * P_ + seg * 12 + k * 4);
#pragma unroll
        for (int u = 0; u < 4; ++u) tile[h * 49 + seg * 12 + k * 4 + u] = v[u];
      }
    }
    __syncthreads();
    if (tid < 192) {
      int p = tid >> 2;
      int hb = (tid & 3) * 16;
      __bf16* dst = w2t + (size_t)e * P_ * H_ + (size_t)(ph * 48 + p) * H_ + hi * 64 + hb;
      bf16x8 o0, o1;
#pragma unroll
      for (int k = 0; k < 8; ++k) o0[k] = (__bf16)tile[(hb + k) * 49 + p];
#pragma unroll
      for (int k = 0; k < 8; ++k) o1[k] = (__bf16)tile[(hb + 8 + k) * 49 + p];
      *(bf16x8*)dst = o0;
      *(bf16x8*)(dst + 8) = o1;
    }
    return;
  }
  if (blk < 1024) {                       // ---- x convert
    size_t i = (size_t)(blk - 512) * 2048 + (size_t)tid * 8;
#pragma unroll
    for (int k = 0; k < 2; ++k) {
      f32x4 v = *(const f32x4*)(x + i + k * 4);
      bf16x4 o = {(__bf16)v[0], (__bf16)v[1], (__bf16)v[2], (__bf16)v[3]};
      *(bf16x4*)(xbf + i + k * 4) = o;
    }
    return;
  }
  if (blk < 1536) {                       // ---- gates: one wave per row m
    int wave = tid >> 6, lane = tid & 63;
    int m = (blk - 1024) * 4 + wave;
    const float* trow = te + (size_t)m * S_;
    float acc[E_];
#pragma unroll
    for (int e = 0; e < E_; ++e) acc[e] = 0.f;
    for (int s = lane; s < S_; s += 64) {
      float t = trow[s];
      const f32x4* wgr = (const f32x4*)(Wg + s * E_);
      f32x4 a = wgr[0], b = wgr[1];
      acc[0] += t * a[0]; acc[1] += t * a[1]; acc[2] += t * a[2]; acc[3] += t * a[3];
      acc[4] += t * b[0]; acc[5] += t * b[1]; acc[6] += t * b[2]; acc[7] += t * b[3];
    }
#pragma unroll
    for (int e = 0; e < E_; ++e) {
#pragma unroll
      for (int off = 32; off > 0; off >>= 1) acc[e] += __shfl_xor(acc[e], off, 64);
    }
    if (lane == 0) {
      float lg[E_];
      float m1 = -3.4e38f, m2 = -3.4e38f;
#pragma unroll
      for (int e = 0; e < E_; ++e) {
        float v = acc[e] + bg[e];
        lg[e] = v;
        if (v > m1) { m2 = m1; m1 = v; }
        else if (v > m2) { m2 = v; }
      }
      float den = 0.f, sm[E_];
#pragma unroll
      for (int e = 0; e < E_; ++e) { sm[e] = expf(lg[e] - m1); den += sm[e]; }
      float inv = 1.f / den;
      float dmax = -3.4e38f, dec[E_];
#pragma unroll
      for (int e = 0; e < E_; ++e) {
        float p = sm[e] * inv;
        float d = (lg[e] < m2) ? (10.f * logf(p + 1.f)) : (10.f * (expf(p) - 1.f));
        dec[e] = d;
        dmax = fmaxf(dmax, d);
      }
      float dden = 0.f;
#pragma unroll
      for (int e = 0; e < E_; ++e) { dec[e] = expf(dec[e] - dmax); dden += dec[e]; }
      float dinv = 1.f / dden;
#pragma unroll
      for (int e = 0; e < E_; ++e) gates[m * E_ + e] = dec[e] * dinv;
    }
    return;
  }
  // ---- zero the accumulated output region [0, M*P)
  {
    size_t i = (size_t)(blk - 1536) * 1024 + (size_t)tid * 4;
    f32x4 z4 = {0.f, 0.f, 0.f, 0.f};
    *(f32x4*)(out + i) = z4;
  }
}

// =================== k_experts: grid (E_, 16, ZSPLIT+1), 512 threads ===================
__global__ __launch_bounds__(512) void k_experts(
    const __bf16* __restrict__ xbf,   // [M][S]
    const __bf16* __restrict__ w1t,   // [E][H][S]
    const __bf16* __restrict__ w2t,   // [E][P][H]
    const float* __restrict__ b1,     // [E][H]
    const float* __restrict__ b2,     // [E][P]
    const float* __restrict__ gates,  // [M][E]
    float* __restrict__ out)          // [M][P] (+2 loss slots)
{
  __shared__ __align__(16) __bf16 W1s[2][BH * BK];  // 64 KB double-buffer [h][k]
  __shared__ __align__(16) __bf16 Xs[2][BM * BK];   // 64 KB double-buffer [m][k]
  __shared__ __align__(16) __bf16 Hs[BM * BH];      // 32 KB [m][h]
                                                    // 163840 B = exactly 160 KiB

  const int tid = threadIdx.x;

  if (blockIdx.z == ZSPLIT) {      // ---- loss block (others exit)
    if (blockIdx.x != 0 || blockIdx.y != 0) return;
    float* gsum = (float*)&Xs[0][0];
    float* cvs  = gsum + F_ * E_;
    float* ents = cvs + F_;
    if (tid < 256) {
      int f = tid >> 3, ee = tid & 7;
      float s = 0.f;
      for (int b = 0; b < B_; ++b) s += gates[(size_t)(b * F_ + f) * E_ + ee];
      gsum[f * E_ + ee] = s;
    }
    __syncthreads();
    if (tid < F_) {
      float mean = 0.f;
#pragma unroll
      for (int k = 0; k < E_; ++k) mean += gsum[tid * E_ + k];
      mean *= (1.f / E_);
      float ss = 0.f;
#pragma unroll
      for (int k = 0; k < E_; ++k) { float d = gsum[tid * E_ + k] - mean; ss += d * d; }
      float var = (float)P_ * ss / (float)(E_ * P_ - 1);
      cvs[tid] = var / (mean * mean + 1e-10f);
      float ent = 0.f;
#pragma unroll
      for (int k = 0; k < E_; ++k) { float g = gsum[tid * E_ + k] * (1.f / B_); ent += -g * logf(g + 1e-8f); }
      ents[tid] = ent * (1.f / E_);
    }
    __syncthreads();
    if (tid == 0) {
      float a = 0.f, b = 0.f;
      for (int k = 0; k < F_; ++k) { a += cvs[k]; b += ents[k]; }
      out[(size_t)M_ * P_ + 0] = a;
      out[(size_t)M_ * P_ + 1] = b;
    }
    return;
  }

  const int wave = tid >> 6, lane = tid & 63;
  const int l15 = lane & 15, quad = lane >> 4;
  const int e = blockIdx.x;
  const int m0 = blockIdx.y * BM;
  const int hz = blockIdx.z * HPZ;

  // staging decomposition: rows have 256B (16 granules of 16B). GLL16 covers
  // 4 rows; lane -> row = base + (lane>>4), phys granule = lane&15.
  // Swizzle: phys_g = logical_g ^ (row&15)  =>  source logical col for lane =
  // (lane&15) ^ (p*4 + lane>>4)  (wave base is a multiple of 16).
  const int sg4 = lane & 15;
  const int sr4 = lane >> 4;            // 0..3
  int sw[4];
#pragma unroll
  for (int p = 0; p < 4; ++p) sw[p] = (sg4 ^ (p * 4 + sr4)) * 8;   // element offset

  const __bf16* w1row = w1t + ((size_t)e * H_ + hz + wave * 16 + sr4) * S_;
  const __bf16* xrow  = xbf + (size_t)(m0 + wave * 16 + sr4) * S_;
  const __bf16* w2z   = w2t + (size_t)e * P_ * H_ + hz;

  // GEMM1 wave tile 64h x 32m (2h x 4m wave grid over 128h x 128m)
  const int hq = (wave & 1) * 64;
  const int mq = (wave >> 1) * 32;
  // GEMM2: 16 m-rows per wave
  const int w16 = wave * 16;

  const f32x4 fz = {0.f, 0.f, 0.f, 0.f};
  f32x4 acc1[4][2];
  f32x4 acc2[6];
#pragma unroll
  for (int j = 0; j < 6; ++j) acc2[j] = fz;

  // ---- stage one 128x128 W1 tile + 128x128 X tile (8 GLL16/wave) ----
  auto STAGE = [&](int slot, int ht_, int kc_) {
    const __bf16* w1p = w1row + (size_t)(ht_ * BH) * S_ + kc_ * BK;
    const __bf16* xp  = xrow + kc_ * BK;
#pragma unroll
    for (int p = 0; p < 4; ++p) {
      GLL16(w1p + (size_t)(p * 4) * S_ + sw[p], &W1s[slot][(wave * 16 + p * 4) * BK]);
      GLL16(xp  + (size_t)(p * 4) * S_ + sw[p], &Xs[slot][(wave * 16 + p * 4) * BK]);
    }
  };

  // ---- GEMM1 compute of one staged tile pair: 32 MFMA/wave ----
  auto COMPUTE = [&](int slot) {
#pragma unroll
    for (int kk = 0; kk < 4; ++kk) {
      const int gq = (((kk * 4 + quad) ^ l15) * 8);
      bf16x8 af[4], bx[2];
#pragma unroll
      for (int i = 0; i < 4; ++i)
        af[i] = *(const bf16x8*)&W1s[slot][(hq + i * 16 + l15) * BK + gq];
#pragma unroll
      for (int j = 0; j < 2; ++j)
        bx[j] = *(const bf16x8*)&Xs[slot][(mq + j * 16 + l15) * BK + gq];
#pragma unroll
      for (int i = 0; i < 4; ++i)
#pragma unroll
        for (int j = 0; j < 2; ++j)
          acc1[i][j] = MFMA16(af[i], bx[j], acc1[i][j]);
    }
  };

  // ---- GEMM2 over Hs chunk htc (k-extent 128): 24 MFMA/wave; W2 direct from L2 ----
  auto GEMM2 = [&](int htc) {
    const __bf16* w2c = w2z + htc * BH;
#pragma unroll
    for (int kk = 0; kk < 4; ++kk) {
      int ab = (w16 + l15) * 256 + (((kk * 4 + quad) ^ l15) * 16);
      bf16x8 a = *(const bf16x8*)((const char*)Hs + ab);
#pragma unroll
      for (int j = 0; j < 6; ++j) {
        bf16x8 bb = *(const bf16x8*)(w2c + (size_t)(j * 16 + l15) * H_ + kk * 32 + quad * 8);
        acc2[j] = MFMA16(a, bb, acc2[j]);
      }
    }
  };

  // ---- bias + gelu -> Hs[m][h] (C-layout: col=l15=m, row=quad*4+r=h), swizzled
  auto GELU = [&](int ht_) {
    const float* b1w = b1 + (size_t)e * H_ + hz + ht_ * BH;
#pragma unroll
    for (int i = 0; i < 4; ++i) {
      int h = hq + i * 16 + quad * 4;
      f32x4 bv = *(const f32x4*)(b1w + h);
#pragma unroll
      for (int j = 0; j < 2; ++j) {
        bf16x4 hv;
#pragma unroll
        for (int r = 0; r < 4; ++r)
          hv[r] = (__bf16)fast_gelu(acc1[i][j][r] + bv[r]);
        int m = mq + j * 16 + l15;
        int wb = m * 256 + (((h >> 3) ^ l15) * 16) + (quad & 1) * 8;
        *(bf16x4*)((char*)Hs + wb) = hv;
      }
    }
  };

  // ================== main pipeline (proven __syncthreads protocol) ==================
  STAGE(0, 0, 0);
  __syncthreads();

  for (int ht = 0; ht < NHT; ++ht) {
#pragma unroll
    for (int i = 0; i < 4; ++i)
#pragma unroll
      for (int j = 0; j < 2; ++j) acc1[i][j] = fz;

#pragma unroll
    for (int kc = 0; kc < NKC; ++kc) {
      // stage next tile pair into the alternate buffer (tile t's buffer = kc&1)
      if (kc < NKC - 1) {
        STAGE((kc + 1) & 1, ht, kc + 1);
      } else if (ht < NHT - 1) {
        STAGE(0, ht + 1, 0);               // next chunk kc=0 -> slot (3+1)&1 = 0
      }
      // previous chunk's GEMM2 runs inside this step (extra MFMA in the window)
      if (kc == 0 && ht > 0) GEMM2(ht - 1);

      COMPUTE(kc & 1);
      __syncthreads();           // drains GLL16 + makes next tile visible
    }
    GELU(ht);
    __syncthreads();             // Hs visible to all waves
  }
  GEMM2(NHT - 1);

  // ---- epilogue: out[m,p] += gates[m,e] * (acc + b2 (z==0 only)) ----
#pragma unroll
  for (int r = 0; r < 4; ++r) {
    int m = m0 + w16 + quad * 4 + r;
    float g = gates[m * E_ + e];
#pragma unroll
    for (int j = 0; j < 6; ++j) {
      int col = j * 16 + l15;
      float v = acc2[j][r];
      if (blockIdx.z == 0) v += b2[e * P_ + col];
      atomicAdd(&out[(size_t)m * P_ + col], g * v);
    }
  }
}

extern "C" void kernel_launch(void* const* d_in, const int* in_sizes, int n_in,
                              void* d_out, int out_size, void* d_ws, size_t ws_size,
                              hipStream_t stream) {
  const float* x  = (const float*)d_in[0];
  const float* te = (const float*)d_in[1];
  const float* Wg = (const float*)d_in[2];
  const float* bg = (const float*)d_in[3];
  const float* W1 = (const float*)d_in[4];
  const float* b1 = (const float*)d_in[5];
  const float* W2 = (const float*)d_in[6];
  const float* b2 = (const float*)d_in[7];
  float* out = (float*)d_out;

  char* ws = (char*)d_ws;
  float* gates = (float*)ws;                                    // 65,536 B
  __bf16* xbf  = (__bf16*)(ws + 65536);                         // 2 MB
  __bf16* w1t  = (__bf16*)(ws + 65536 + 2097152);               // 16 MB
  __bf16* w2t  = (__bf16*)(ws + 65536 + 2097152 + 16777216);    // 3 MB

  k_prep_w1<<<2048, 256, 0, stream>>>(W1, w1t);
  k_prep_rest<<<1728, 256, 0, stream>>>(x, te, Wg, bg, W2, xbf, w2t, gates, out);
  k_experts<<<dim3(E_, M_ / BM, ZSPLIT + 1), 512, 0, stream>>>(xbf, w1t, w2t, b1, b2, gates, out);
}

// Round 7
// 184.847 us; speedup vs baseline: 1.1610x; 1.1610x over previous
//
#include <hip/hip_runtime.h>
#include <math.h>

#define B_ 64
#define F_ 32
#define S_ 512
#define P_ 96
#define E_ 8
#define H_ 2048
#define M_ 2048   // B_*F_ rows, m = b*F_ + f

// ---- k_experts: r1 structure (best measured: 88.0us) + two fixes ----
// r6 post-mortem: counted-vmcnt/raw-barrier protocols abandoned (r2 pathological
// 31ms dispatch; r6 hung container). This round = proven r1 __syncthreads+GLL16
// pipeline with its two measured defects fixed:
//   1) Hs HPITCH=136 -> byte-XOR-swizzled [128][128] (r1: 2.36M conflict cycles;
//      r5's swizzle formula pair, numerically validated by r5's passing run).
//   2) GEMM2's 24 MFMA spread over kc=0..3 (6 each) instead of all at kc==0 --
//      smooths latency-hiding work across steps, identical barrier structure.
#define BM 128            // m rows per block
#define BH 128            // h per chunk
#define BK 64             // k per staged tile
#define ZSPLIT 2
#define HPZ (H_ / ZSPLIT) // 1024 h per z-block
#define NHT (HPZ / BH)    // 8 h-chunks per block
#define NKC (S_ / BK)     // 8 k-steps per chunk

typedef __bf16 bf16x8 __attribute__((ext_vector_type(8)));
typedef __bf16 bf16x4 __attribute__((ext_vector_type(4)));
typedef float f32x4 __attribute__((ext_vector_type(4)));

#define MFMA16(a, b, c) __builtin_amdgcn_mfma_f32_16x16x32_bf16((a), (b), (c), 0, 0, 0)

// async global->LDS, 16B per lane; LDS dest is wave-uniform base + lane*16
#define GLL16(gp, lp) __builtin_amdgcn_global_load_lds(                     \
    (const __attribute__((address_space(1))) void*)(gp),                    \
    (__attribute__((address_space(3))) void*)(lp), 16, 0, 0)

// sigmoid-approx gelu: x * sigmoid(1.702 x)  (absmax 0.0098 measured — 17x margin)
__device__ __forceinline__ float fast_gelu(float x) {
  float e = __builtin_amdgcn_exp2f(-2.45546696f * x);
  return x * __builtin_amdgcn_rcpf(1.0f + e);
}

// =================== k_prep (256 threads): transposes + convert + gates + out-zero ===================
// blocks [0,2048):     W1 [E][S][H] f32 -> w1t [E][H][S] bf16   (64x64 tiles)
// blocks [2048,2560):  W2 [E][H][P] f32 -> w2t [E][P][H] bf16   (64h x 48p tiles)
// blocks [2560,3072):  x convert (8 elems/thread)
// blocks [3072,3584):  gates (4 rows per block)
// blocks [3584,3776):  zero out[M*P]
#define PREP_GRID 3776

__global__ __launch_bounds__(256) void k_prep(const float* __restrict__ x,
                                              const float* __restrict__ te,
                                              const float* __restrict__ Wg,
                                              const float* __restrict__ bg,
                                              const float* __restrict__ W1,
                                              const float* __restrict__ W2,
                                              __bf16* __restrict__ xbf,
                                              __bf16* __restrict__ w1t,
                                              __bf16* __restrict__ w2t,
                                              float* __restrict__ gates,
                                              float* __restrict__ out) {
  __shared__ float tile[64 * 65];
  const int blk = blockIdx.x;
  const int tid = threadIdx.x;

  if (blk < 2048) {                       // ---- W1 transpose: tile 64s x 64h
    int e = blk >> 8, tt = blk & 255;
    int si = tt >> 5, hi = tt & 31;
    const float* src = W1 + (size_t)e * S_ * H_ + (size_t)(si * 64) * H_ + hi * 64;
    {
      int row = tid >> 2;
      int cb = (tid & 3) * 16;
#pragma unroll
      for (int k = 0; k < 4; ++k) {
        f32x4 v = *(const f32x4*)(src + (size_t)row * H_ + cb + k * 4);
#pragma unroll
        for (int u = 0; u < 4; ++u) tile[row * 65 + cb + k * 4 + u] = v[u];
      }
    }
    __syncthreads();
    {
      int h = tid >> 2;
      int sb = (tid & 3) * 16;
      __bf16* dst = w1t + (size_t)e * H_ * S_ + (size_t)(hi * 64 + h) * S_ + si * 64 + sb;
      bf16x8 o0, o1;
#pragma unroll
      for (int k = 0; k < 8; ++k) o0[k] = (__bf16)tile[(sb + k) * 65 + h];
#pragma unroll
      for (int k = 0; k < 8; ++k) o1[k] = (__bf16)tile[(sb + 8 + k) * 65 + h];
      *(bf16x8*)dst = o0;
      *(bf16x8*)(dst + 8) = o1;
    }
    return;
  }
  if (blk < 2560) {                       // ---- W2 transpose: tile 64h x 48p
    int t = blk - 2048;
    int e = t >> 6, hi = (t >> 1) & 31, ph = t & 1;
    const float* src = W2 + (size_t)e * H_ * P_ + (size_t)(hi * 64) * P_ + ph * 48;
    {
      int h = tid & 63;
      int seg = tid >> 6;
#pragma unroll
      for (int k = 0; k < 3; ++k) {
        f32x4 v = *(const f32x4*)(src + (size_t)h * P_ + seg * 12 + k * 4);
#pragma unroll
        for (int u = 0; u < 4; ++u) tile[h * 49 + seg * 12 + k * 4 + u] = v[u];
      }
    }
    __syncthreads();
    if (tid < 192) {
      int p = tid >> 2;
      int hb = (tid & 3) * 16;
      __bf16* dst = w2t + (size_t)e * P_ * H_ + (size_t)(ph * 48 + p) * H_ + hi * 64 + hb;
      bf16x8 o0, o1;
#pragma unroll
      for (int k = 0; k < 8; ++k) o0[k] = (__bf16)tile[(hb + k) * 49 + p];
#pragma unroll
      for (int k = 0; k < 8; ++k) o1[k] = (__bf16)tile[(hb + 8 + k) * 49 + p];
      *(bf16x8*)dst = o0;
      *(bf16x8*)(dst + 8) = o1;
    }
    return;
  }
  if (blk < 3072) {                       // ---- x convert
    size_t i = (size_t)(blk - 2560) * 2048 + (size_t)tid * 8;
#pragma unroll
    for (int k = 0; k < 2; ++k) {
      f32x4 v = *(const f32x4*)(x + i + k * 4);
      bf16x4 o = {(__bf16)v[0], (__bf16)v[1], (__bf16)v[2], (__bf16)v[3]};
      *(bf16x4*)(xbf + i + k * 4) = o;
    }
    return;
  }
  if (blk < 3584) {                       // ---- gates: one wave per row m
    int wave = tid >> 6, lane = tid & 63;
    int m = (blk - 3072) * 4 + wave;
    const float* trow = te + (size_t)m * S_;
    float acc[E_];
#pragma unroll
    for (int e = 0; e < E_; ++e) acc[e] = 0.f;
    for (int s = lane; s < S_; s += 64) {
      float t = trow[s];
      const f32x4* wgr = (const f32x4*)(Wg + s * E_);
      f32x4 a = wgr[0], b = wgr[1];
      acc[0] += t * a[0]; acc[1] += t * a[1]; acc[2] += t * a[2]; acc[3] += t * a[3];
      acc[4] += t * b[0]; acc[5] += t * b[1]; acc[6] += t * b[2]; acc[7] += t * b[3];
    }
#pragma unroll
    for (int e = 0; e < E_; ++e) {
#pragma unroll
      for (int off = 32; off > 0; off >>= 1) acc[e] += __shfl_xor(acc[e], off, 64);
    }
    if (lane == 0) {
      float lg[E_];
      float m1 = -3.4e38f, m2 = -3.4e38f;
#pragma unroll
      for (int e = 0; e < E_; ++e) {
        float v = acc[e] + bg[e];
        lg[e] = v;
        if (v > m1) { m2 = m1; m1 = v; }
        else if (v > m2) { m2 = v; }
      }
      float den = 0.f, sm[E_];
#pragma unroll
      for (int e = 0; e < E_; ++e) { sm[e] = expf(lg[e] - m1); den += sm[e]; }
      float inv = 1.f / den;
      float dmax = -3.4e38f, dec[E_];
#pragma unroll
      for (int e = 0; e < E_; ++e) {
        float p = sm[e] * inv;
        float d = (lg[e] < m2) ? (10.f * logf(p + 1.f)) : (10.f * (expf(p) - 1.f));
        dec[e] = d;
        dmax = fmaxf(dmax, d);
      }
      float dden = 0.f;
#pragma unroll
      for (int e = 0; e < E_; ++e) { dec[e] = expf(dec[e] - dmax); dden += dec[e]; }
      float dinv = 1.f / dden;
#pragma unroll
      for (int e = 0; e < E_; ++e) gates[m * E_ + e] = dec[e] * dinv;
    }
    return;
  }
  // ---- zero the accumulated output region [0, M*P)
  {
    size_t i = (size_t)(blk - 3584) * 1024 + (size_t)tid * 4;
    f32x4 z4 = {0.f, 0.f, 0.f, 0.f};
    *(f32x4*)(out + i) = z4;
  }
}

// =================== k_experts: grid (E_, 16, ZSPLIT+1), 512 threads ===================
__global__ __launch_bounds__(512, 2) void k_experts(
    const __bf16* __restrict__ xbf,   // [M][S]
    const __bf16* __restrict__ w1t,   // [E][H][S]
    const __bf16* __restrict__ w2t,   // [E][P][H]
    const float* __restrict__ b1,     // [E][H]
    const float* __restrict__ b2,     // [E][P]
    const float* __restrict__ gates,  // [M][E]
    float* __restrict__ out)          // [M][P] (+2 loss slots)
{
  __shared__ __align__(16) __bf16 W1s[2][BH * BK];   // 32 KB dbuf [h][k], granule-swz
  __shared__ __align__(16) __bf16 Xs[2][BM * BK];    // 32 KB dbuf [m][k], granule-swz
  __shared__ __align__(16) __bf16 W2s[P_ * BH];      // 24 KB [p][h], granule-swz
  __shared__ __align__(16) __bf16 Hs[BM * BH];       // 32 KB [m][h], byte-XOR swz
                                                     // 120 KB total -> 1 block/CU

  const int tid = threadIdx.x;

  if (blockIdx.z == ZSPLIT) {      // ---- loss block (others exit)
    if (blockIdx.x != 0 || blockIdx.y != 0) return;
    float* gsum = (float*)&W1s[0][0];
    float* cvs  = gsum + F_ * E_;
    float* ents = cvs + F_;
    if (tid < 256) {
      int f = tid >> 3, ee = tid & 7;
      float s = 0.f;
      for (int b = 0; b < B_; ++b) s += gates[(size_t)(b * F_ + f) * E_ + ee];
      gsum[f * E_ + ee] = s;
    }
    __syncthreads();
    if (tid < F_) {
      float mean = 0.f;
#pragma unroll
      for (int k = 0; k < E_; ++k) mean += gsum[tid * E_ + k];
      mean *= (1.f / E_);
      float ss = 0.f;
#pragma unroll
      for (int k = 0; k < E_; ++k) { float d = gsum[tid * E_ + k] - mean; ss += d * d; }
      float var = (float)P_ * ss / (float)(E_ * P_ - 1);
      cvs[tid] = var / (mean * mean + 1e-10f);
      float ent = 0.f;
#pragma unroll
      for (int k = 0; k < E_; ++k) { float g = gsum[tid * E_ + k] * (1.f / B_); ent += -g * logf(g + 1e-8f); }
      ents[tid] = ent * (1.f / E_);
    }
    __syncthreads();
    if (tid == 0) {
      float a = 0.f, b = 0.f;
      for (int k = 0; k < F_; ++k) { a += cvs[k]; b += ents[k]; }
      out[(size_t)M_ * P_ + 0] = a;
      out[(size_t)M_ * P_ + 1] = b;
    }
    return;
  }

  const int wave = tid >> 6, lane = tid & 63;
  const int l15 = lane & 15, quad = lane >> 4;
  const int e = blockIdx.x;
  const int m0 = blockIdx.y * BM;
  const int hz = blockIdx.z * HPZ;

  // staging decomposition: lane -> (row-in-8-group srl, granule sg); swizzle sg^srl
  const int sg = lane & 7;
  const int srl = lane >> 3;            // 0..7
  const int gcol = ((sg ^ srl) * 8);    // swizzled source column (elements)

  const __bf16* w1base = w1t + ((size_t)e * H_ + hz + wave * 16 + srl) * S_ + gcol;
  const __bf16* xg = xbf + (size_t)(m0 + wave * 16 + srl) * S_ + gcol;
  const __bf16* w2z = w2t + (size_t)e * P_ * H_ + hz;

  // GEMM1 wave quadrant: 64h x 32m per wave (2x4 wave grid over 128x128)
  const int hq = (wave & 1) * 64;
  const int mq = (wave >> 1) * 32;
  // GEMM2: 16 m-rows per wave
  const int w16 = wave * 16;

  const f32x4 fz = {0.f, 0.f, 0.f, 0.f};
  f32x4 acc1[4][2];
  f32x4 acc2[6];
#pragma unroll
  for (int j = 0; j < 6; ++j) acc2[j] = fz;

  // ---- stage one 128x64 W1 tile + 128x64 X tile into buffer b (4 GLL16/wave) ----
  auto STAGE = [&](int ht_, int kc_, int b) {
    const __bf16* w1p = w1base + (size_t)(ht_ * BH) * S_ + kc_ * BK;
    const __bf16* xp  = xg + kc_ * BK;
#pragma unroll
    for (int p = 0; p < 2; ++p) {
      GLL16(w1p + (size_t)(p * 8) * S_, &W1s[b][(wave * 16 + p * 8) * BK]);
      GLL16(xp  + (size_t)(p * 8) * S_, &Xs[b][(wave * 16 + p * 8) * BK]);
    }
  };

  // ---- stage W2 panel [96p][128h] for chunk ht_ (3 GLL16/wave), swizzled source ----
  auto STAGEW2 = [&](int ht_) {
#pragma unroll
    for (int p = 0; p < 3; ++p) {
      int r2 = wave * 12 + p * 4 + quad;        // p-row 0..95
      GLL16(w2z + (size_t)r2 * H_ + ht_ * BH + ((l15 ^ (r2 & 7)) * 8),
            &W2s[(wave * 12 + p * 4) * BH]);
    }
  };

  // ---- GEMM1 compute of the tile in buffer b: 16 MFMA/wave ----
  auto COMPUTE = [&](int b) {
#pragma unroll
    for (int kk = 0; kk < 2; ++kk) {
      bf16x8 af[4], bx[2];
#pragma unroll
      for (int i = 0; i < 4; ++i) {
        int r = hq + i * 16 + l15;
        af[i] = *(const bf16x8*)&W1s[b][r * BK + (((kk * 4 + quad) ^ (r & 7)) * 8)];
      }
#pragma unroll
      for (int j = 0; j < 2; ++j) {
        int r = mq + j * 16 + l15;
        bx[j] = *(const bf16x8*)&Xs[b][r * BK + (((kk * 4 + quad) ^ (r & 7)) * 8)];
      }
#pragma unroll
      for (int i = 0; i < 4; ++i)
#pragma unroll
        for (int j = 0; j < 2; ++j)
          acc1[i][j] = MFMA16(af[i], bx[j], acc1[i][j]);
    }
  };

  // ---- GEMM2 quarter kk over Hs + W2s (both LDS): 6 MFMA/wave ----
  auto GEMM2Q = [&](int kk) {
    int ab = (w16 + l15) * 256 + (((kk * 4 + quad) ^ l15) * 16);
    bf16x8 a = *(const bf16x8*)((const char*)Hs + ab);
#pragma unroll
    for (int j = 0; j < 6; ++j) {
      bf16x8 bb = *(const bf16x8*)&W2s[(j * 16 + l15) * BH + (((kk * 4 + quad) ^ (l15 & 7)) * 8)];
      acc2[j] = MFMA16(a, bb, acc2[j]);
    }
  };

  // ---- bias + gelu -> Hs (C-layout: col=l15=m, row=quad*4+r=h), byte-XOR swz ----
  auto GELU = [&](int ht_) {
    const float* b1w = b1 + (size_t)e * H_ + hz + ht_ * BH;
#pragma unroll
    for (int i = 0; i < 4; ++i) {
      int h = hq + i * 16 + quad * 4;
      f32x4 bv = *(const f32x4*)(b1w + h);
#pragma unroll
      for (int j = 0; j < 2; ++j) {
        bf16x4 hv;
#pragma unroll
        for (int r = 0; r < 4; ++r)
          hv[r] = (__bf16)fast_gelu(acc1[i][j][r] + bv[r]);
        int m = mq + j * 16 + l15;
        int wb = m * 256 + (((h >> 3) ^ l15) * 16) + (quad & 1) * 8;
        *(bf16x4*)((char*)Hs + wb) = hv;
      }
    }
  };

  // ================== main pipeline (proven r1 __syncthreads protocol) ==================
  STAGE(0, 0, 0);
  __syncthreads();

  for (int ht = 0; ht < NHT; ++ht) {
#pragma unroll
    for (int i = 0; i < 4; ++i)
#pragma unroll
      for (int j = 0; j < 2; ++j) acc1[i][j] = fz;

    int bsel = 0;
#pragma unroll
    for (int kc = 0; kc < NKC; ++kc) {
      if (kc < NKC - 1) {
        STAGE(ht, kc + 1, bsel ^ 1);
      } else {
        if (ht < NHT - 1) STAGE(ht + 1, 0, bsel ^ 1);
        STAGEW2(ht);                    // W2(ht), consumed during chunk ht+1 / tail
      }
      // previous chunk's GEMM2, spread 6 MFMA per step over kc=0..3
      if (kc < 4 && ht > 0) GEMM2Q(kc);

      COMPUTE(bsel);
      __syncthreads();                  // drains GLL16 + makes next tile visible
      bsel ^= 1;
    }
    GELU(ht);
    __syncthreads();                    // Hs(ht) visible to all waves
  }
#pragma unroll
  for (int kk = 0; kk < 4; ++kk) GEMM2Q(kk);   // last chunk

  // ---- epilogue: out[m,p] += gates[m,e] * (acc + b2 (z==0 only)) ----
#pragma unroll
  for (int r = 0; r < 4; ++r) {
    int m = m0 + w16 + quad * 4 + r;
    float g = gates[m * E_ + e];
#pragma unroll
    for (int j = 0; j < 6; ++j) {
      int col = j * 16 + l15;
      float v = acc2[j][r];
      if (blockIdx.z == 0) v += b2[e * P_ + col];
      atomicAdd(&out[(size_t)m * P_ + col], g * v);
    }
  }
}

extern "C" void kernel_launch(void* const* d_in, const int* in_sizes, int n_in,
                              void* d_out, int out_size, void* d_ws, size_t ws_size,
                              hipStream_t stream) {
  const float* x  = (const float*)d_in[0];
  const float* te = (const float*)d_in[1];
  const float* Wg = (const float*)d_in[2];
  const float* bg = (const float*)d_in[3];
  const float* W1 = (const float*)d_in[4];
  const float* b1 = (const float*)d_in[5];
  const float* W2 = (const float*)d_in[6];
  const float* b2 = (const float*)d_in[7];
  float* out = (float*)d_out;

  char* ws = (char*)d_ws;
  float* gates = (float*)ws;                                    // 65,536 B
  __bf16* xbf  = (__bf16*)(ws + 65536);                         // 2 MB
  __bf16* w1t  = (__bf16*)(ws + 65536 + 2097152);               // 16 MB
  __bf16* w2t  = (__bf16*)(ws + 65536 + 2097152 + 16777216);    // 3 MB

  k_prep<<<PREP_GRID, 256, 0, stream>>>(x, te, Wg, bg, W1, W2, xbf, w1t, w2t, gates, out);
  k_experts<<<dim3(E_, M_ / BM, ZSPLIT + 1), 512, 0, stream>>>(xbf, w1t, w2t, b1, b2, gates, out);
}